// Round 8
// baseline (38429.028 us; speedup 1.0000x reference)
//
#include <hip/hip_runtime.h>
#include <hip/hip_bf16.h>

// LSTM T=8192, I=620, H=1000, batch=1.
// Phase 1: xgT[t][e*4+g] = x[t] @ W_ih^T + b   (GEMM -> ws, transposed layout)
// Phase 2: 125 WGs x 320 threads = 4 producer waves + 1 consumer wave.
//   Producer wave v owns h elems {w*8+2v, +1} end-to-end: dot (8 rows x 1000,
//   weights in regs) -> in-wave shfl reduce -> gates -> lane0 publishes both
//   h via global_atomic_swap_x2 (2 LSB mantissa stamp = (t+1)&3), NO drain.
//   Consumer wave gathers all 250 uint4 of h^t in ONE asm block per attempt
//   (4 loads + vmcnt(0), outputs are asm outputs -> no reorder hazard),
//   writes LDS hs[(t+1)&1], feeds 2-deep xg LDS ring. One barrier per step.

#define IN_SZ   620
#define HID     1000
#define G4      4000
#define NWF     125
#define NW_LEG  50
#define EP_LEG  20

__device__ __forceinline__ float sigm(float v)      { return 1.0f / (1.0f + __expf(-v)); }
__device__ __forceinline__ float tanh_fast(float v) { return 2.0f / (1.0f + __expf(-2.0f * v)) - 1.0f; }

__device__ __forceinline__ void stxg_(float* p, float v) { *p = v; }
__device__ __forceinline__ void stxg_(__hip_bfloat16* p, float v) { *p = __float2bfloat16(v); }

// ---------------- Phase 1: xg GEMM, 128x128x16 tiles, 8x8 micro-tile ----------------
// Stores TRANSPOSED: xgT[m*4000 + e*4 + g]  (n = g*1000 + e)
template <typename XG>
__global__ __launch_bounds__(256) void xg_gemm2(
    const float* __restrict__ x,    // (T, 620)
    const float* __restrict__ Wih,  // (4000, 620)
    const float* __restrict__ bih,
    const float* __restrict__ bhh,
    XG* __restrict__ xg,            // (T, 4000) transposed-inner
    int T)
{
    constexpr int BM = 128, BN = 128, BK = 16, LDT = BM + 4;
    __shared__ float As[BK][LDT];
    __shared__ float Bs[BK][LDT];
    const int tid = threadIdx.x;
    const int tx = tid & 15, ty = tid >> 4;
    const int m0 = blockIdx.y * BM, n0 = blockIdx.x * BN;
    float acc[8][8] = {};

    for (int k0 = 0; k0 < IN_SZ; k0 += BK) {
        #pragma unroll
        for (int it = 0; it < 2; ++it) {
            const int r = (tid >> 2) + it * 64;
            const int c = (tid & 3) * 4;
            const int gk = k0 + c;
            {
                const int gm = m0 + r;
                float4 v = {0.f, 0.f, 0.f, 0.f};
                if (gm < T) {
                    if (gk + 3 < IN_SZ) {
                        v = *reinterpret_cast<const float4*>(x + (size_t)gm * IN_SZ + gk);
                    } else {
                        const float* row = x + (size_t)gm * IN_SZ;
                        v.x = (gk + 0 < IN_SZ) ? row[gk + 0] : 0.f;
                        v.y = (gk + 1 < IN_SZ) ? row[gk + 1] : 0.f;
                        v.z = (gk + 2 < IN_SZ) ? row[gk + 2] : 0.f;
                        v.w = (gk + 3 < IN_SZ) ? row[gk + 3] : 0.f;
                    }
                }
                As[c + 0][r] = v.x; As[c + 1][r] = v.y;
                As[c + 2][r] = v.z; As[c + 3][r] = v.w;
            }
            {
                const int gn = n0 + r;
                float4 v = {0.f, 0.f, 0.f, 0.f};
                if (gn < G4) {
                    if (gk + 3 < IN_SZ) {
                        v = *reinterpret_cast<const float4*>(Wih + (size_t)gn * IN_SZ + gk);
                    } else {
                        const float* row = Wih + (size_t)gn * IN_SZ;
                        v.x = (gk + 0 < IN_SZ) ? row[gk + 0] : 0.f;
                        v.y = (gk + 1 < IN_SZ) ? row[gk + 1] : 0.f;
                        v.z = (gk + 2 < IN_SZ) ? row[gk + 2] : 0.f;
                        v.w = (gk + 3 < IN_SZ) ? row[gk + 3] : 0.f;
                    }
                }
                Bs[c + 0][r] = v.x; Bs[c + 1][r] = v.y;
                Bs[c + 2][r] = v.z; Bs[c + 3][r] = v.w;
            }
        }
        __syncthreads();
        #pragma unroll
        for (int k = 0; k < BK; ++k) {
            float a[8], b[8];
            *reinterpret_cast<float4*>(&a[0]) = *reinterpret_cast<const float4*>(&As[k][ty * 8]);
            *reinterpret_cast<float4*>(&a[4]) = *reinterpret_cast<const float4*>(&As[k][ty * 8 + 4]);
            *reinterpret_cast<float4*>(&b[0]) = *reinterpret_cast<const float4*>(&Bs[k][tx * 8]);
            *reinterpret_cast<float4*>(&b[4]) = *reinterpret_cast<const float4*>(&Bs[k][tx * 8 + 4]);
            #pragma unroll
            for (int i = 0; i < 8; ++i)
                #pragma unroll
                for (int j = 0; j < 8; ++j)
                    acc[i][j] = fmaf(a[i], b[j], acc[i][j]);
        }
        __syncthreads();
    }

    float bias[8];
    #pragma unroll
    for (int j = 0; j < 8; ++j) {
        const int n = n0 + tx * 8 + j;
        bias[j] = (n < G4) ? (bih[n] + bhh[n]) : 0.f;
    }
    #pragma unroll
    for (int i = 0; i < 8; ++i) {
        const int m = m0 + ty * 8 + i;
        if (m >= T) continue;
        #pragma unroll
        for (int j = 0; j < 8; ++j) {
            const int n = n0 + tx * 8 + j;
            if (n < G4) {
                const int g = n / 1000, e = n - g * 1000;
                stxg_(&xg[(size_t)m * G4 + e * 4 + g], acc[i][j] + bias[j]);
            }
        }
    }
}

// ---------------- Phase 2 ----------------
template <int MODE>
__device__ __forceinline__ float ldxg(const void* xg_v, size_t idx) {
    if (MODE == 0) return ((const float*)xg_v)[idx];
    return __bfloat162float(((const __hip_bfloat16*)xg_v)[idx]);
}

template <int MODE>
__global__ __launch_bounds__(320, 1) void lstm_fast4(
    const void* __restrict__ xg_v,   // xgT (T,4000) [e*4+g]
    const float* __restrict__ Whh,   // (4000, 1000)
    float* __restrict__ out,         // (T, 1000)
    unsigned* hb_u,                  // 2 * 1024 u32 (double-buffered, stamped)
    int T)
{
    __shared__ __align__(16) unsigned hs[2][1024];
    __shared__ float xr_s[2][32];    // xg ring (2-deep)

    const int w = blockIdx.x, tid = threadIdx.x;
    const int wave = tid >> 6, lane = tid & 63;

    for (int i = tid; i < 2048; i += 320) ((unsigned*)hs)[i] = 0u;
    if (wave == 4 && lane < 32)      // prefill ring slot 0 (step 0)
        xr_s[0][lane] = ldxg<MODE>(xg_v, (size_t)w * 32 + lane);
    __syncthreads();

    // ---- producer lane roles ----
    const int e  = lane >> 5;          // elem parity (0/1)
    const int p  = (lane >> 3) & 3;    // gate
    const int k  = lane & 7;           // column-slice index within row
    const int we0w = w * 8 + wave * 2; // wave's 2 global h indices

    // ---- weight preload: row (p*HID + we0w + e), chunks k+8m + tail ----
    float4 wreg[32];
    if (wave < 4) {
        const int gr = p * HID + we0w + e;
        const float* wrow = Whh + (size_t)gr * HID;
        #pragma unroll
        for (int m = 0; m < 31; ++m)
            wreg[m] = *reinterpret_cast<const float4*>(wrow + (k + 8 * m) * 4);
        wreg[31] = (k < 2) ? *reinterpret_cast<const float4*>(wrow + (k + 248) * 4)
                           : float4{0.f, 0.f, 0.f, 0.f};
    }
    const int tail_c = (k < 2) ? (k + 248) : k;

    float c_reg = 0.0f;                // lanes 0/32 of producer waves

    // consumer state: xg for step t+1, loaded one step ahead
    float xnext = 0.f;
    if (wave == 4 && lane < 32 && 1 < T)
        xnext = ldxg<MODE>(xg_v, (size_t)1 * G4 + w * 32 + lane);

    for (int t = 0;;) {
        if (wave < 4) {
            // ================= producer =================
            const float* hsf = reinterpret_cast<const float*>(&hs[t & 1][0]);
            float a0 = 0.f, a1 = 0.f, a2 = 0.f, a3 = 0.f;
            #pragma unroll
            for (int m = 0; m < 31; ++m) {
                const float4 hv = *reinterpret_cast<const float4*>(hsf + (k + 8 * m) * 4);
                const float s = fmaf(wreg[m].x, hv.x, fmaf(wreg[m].y, hv.y,
                                fmaf(wreg[m].z, hv.z, wreg[m].w * hv.w)));
                if ((m & 3) == 0) a0 += s; else if ((m & 3) == 1) a1 += s;
                else if ((m & 3) == 2) a2 += s; else a3 += s;
            }
            {
                const float4 hv = *reinterpret_cast<const float4*>(hsf + tail_c * 4);
                a3 += fmaf(wreg[31].x, hv.x, fmaf(wreg[31].y, hv.y,
                      fmaf(wreg[31].z, hv.z, wreg[31].w * hv.w)));
            }
            float acc = (a0 + a1) + (a2 + a3);
            acc += __shfl_xor(acc, 1);
            acc += __shfl_xor(acc, 2);
            acc += __shfl_xor(acc, 4);   // all 8 lanes of the row now hold the sum

            // redistribute: lane base+q (q<4) takes (e, gate q)
            const float gsumv = __shfl(acc, (lane & 32) + (lane & 3) * 8);
            const float xv = xr_s[t & 1][(wave * 2 + e) * 4 + (lane & 3)];
            const float gg = gsumv + xv;
            const float actv = ((lane & 3) == 2) ? tanh_fast(gg) : sigm(gg);

            const int base = lane & 32;
            const float iv = __shfl(actv, base + 0);
            const float fv = __shfl(actv, base + 1);
            const float gv = __shfl(actv, base + 2);
            const float ov = __shfl(actv, base + 3);
            float hval = 0.f;
            if ((lane & 31) == 0) {
                c_reg = fv * c_reg + iv * gv;
                hval = ov * tanh_fast(c_reg);
            }
            const float h1 = __shfl(hval, 32);
            if (lane == 0) {
                const unsigned st = (unsigned)((t + 1) & 3);
                const unsigned u0 = (__float_as_uint(hval) & ~3u) | st;
                const unsigned u1 = (__float_as_uint(h1)   & ~3u) | st;
                const unsigned long long dat =
                    (unsigned long long)u0 | ((unsigned long long)u1 << 32);
                const unsigned long long addr =
                    (unsigned long long)(uintptr_t)(hb_u + (t & 1) * 1024 + we0w);
                asm volatile("global_atomic_swap_x2 %0, %1, off"
                             :: "v"(addr), "v"(dat) : "memory");
                float2 o2; o2.x = hval; o2.y = h1;
                *reinterpret_cast<float2*>(out + (size_t)t * HID + we0w) = o2;
                // no drain: ack retires in background; barrier handles ordering
            }
        } else {
            // ================= consumer =================
            // (a) xg ring slot for step t+1 (xnext landed >=1 step ago)
            if (lane < 32 && t + 1 < T) xr_s[(t + 1) & 1][lane] = xnext;

            if (t + 1 < T) {
                // (b) gather h^t -> hs[(t+1)&1]; 4 slots per lane, one asm
                //     block per attempt (loads + vmcnt(0) + outputs together)
                const unsigned want = (unsigned)(t + 1) & 3u;
                const uint4* srcb =
                    reinterpret_cast<const uint4*>(hb_u + (t & 1) * 1024);
                const bool has3 = (192 + lane) < 250;
                const uint4* p0 = srcb + lane;
                const uint4* p1 = srcb + 64 + lane;
                const uint4* p2 = srcb + 128 + lane;
                const uint4* p3 = srcb + (has3 ? 192 + lane : 0);
                uint4 v0, v1, v2, v3;
                for (;;) {
                    asm volatile(
                        "global_load_dwordx4 %0, %4, off sc0 sc1\n\t"
                        "global_load_dwordx4 %1, %5, off sc0 sc1\n\t"
                        "global_load_dwordx4 %2, %6, off sc0 sc1\n\t"
                        "global_load_dwordx4 %3, %7, off sc0 sc1\n\t"
                        "s_waitcnt vmcnt(0)"
                        : "=&v"(v0), "=&v"(v1), "=&v"(v2), "=&v"(v3)
                        : "v"(p0), "v"(p1), "v"(p2), "v"(p3)
                        : "memory");
                    unsigned bad =
                        ((v0.x ^ want) | (v0.y ^ want) | (v0.z ^ want) | (v0.w ^ want) |
                         (v1.x ^ want) | (v1.y ^ want) | (v1.z ^ want) | (v1.w ^ want) |
                         (v2.x ^ want) | (v2.y ^ want) | (v2.z ^ want) | (v2.w ^ want)) & 3u;
                    if (has3)
                        bad |= ((v3.x ^ want) | (v3.y ^ want) |
                                (v3.z ^ want) | (v3.w ^ want)) & 3u;
                    if (bad == 0u) break;
                }
                uint4* dst = reinterpret_cast<uint4*>(&hs[(t + 1) & 1][0]);
                dst[lane] = v0;
                dst[64 + lane] = v1;
                dst[128 + lane] = v2;
                if (has3) dst[192 + lane] = v3;

                // (c) issue xg load for step t+2 (hides under next step)
                if (lane < 32 && t + 2 < T)
                    xnext = ldxg<MODE>(xg_v, (size_t)(t + 2) * G4 + w * 32 + lane);
            }
        }

        if (++t >= T) break;
        __syncthreads();   // joins producer publish epoch & consumer fill
    }
}

// ---------------- legacy fallback (tiny ws): fused x-projection ----------------
__global__ __launch_bounds__(256, 1) void lstm_seq_legacy(
    const float* __restrict__ x,
    const float* __restrict__ Wih,
    const float* __restrict__ Whh,
    const float* __restrict__ bih,
    const float* __restrict__ bhh,
    float* __restrict__ out,
    float* hbuf, unsigned* flags, int T)
{
    __shared__ __align__(16) float h_s[HID];
    __shared__ __align__(16) float x_s[IN_SZ + 4];
    __shared__ float pre[4][EP_LEG];

    const int w = blockIdx.x, tid = threadIdx.x;
    const int wave = tid >> 6, lane = tid & 63;
    const int i16 = lane & 15, p = lane >> 4;
    const int e0 = w * EP_LEG;

    for (int i = tid; i < HID; i += 256) h_s[i] = 0.0f;
    for (int i = tid; i < IN_SZ; i += 256) x_s[i] = x[i];
    __syncthreads();

    const float* wb_h = Whh + ((size_t)wave * HID + e0) * HID;
    const float* wb_x = Wih + ((size_t)wave * HID + e0) * IN_SZ;
    float c_reg = 0.0f;
    float bsum[4] = {0.f, 0.f, 0.f, 0.f};
    if (wave == 0 && lane < EP_LEG) {
        #pragma unroll
        for (int g = 0; g < 4; ++g) {
            int n = g * HID + e0 + lane;
            bsum[g] = bih[n] + bhh[n];
        }
    }

    for (int t = 0;;) {
        #pragma unroll
        for (int pass = 0; pass < EP_LEG / 4; ++pass) {
            const int e = pass * 4 + p;
            const float* wr = wb_h + (size_t)e * HID;
            float a0 = 0.f, a1 = 0.f, a2 = 0.f, a3 = 0.f;
            #pragma unroll
            for (int m = 0; m < 15; ++m) {
                const int kk = i16 * 4 + m * 64;
                const float4 wv = *reinterpret_cast<const float4*>(wr + kk);
                const float4 hv = *reinterpret_cast<const float4*>(&h_s[kk]);
                const float s = fmaf(wv.x, hv.x, fmaf(wv.y, hv.y, fmaf(wv.z, hv.z, wv.w * hv.w)));
                if ((m & 3) == 0) a0 += s; else if ((m & 3) == 1) a1 += s;
                else if ((m & 3) == 2) a2 += s; else a3 += s;
            }
            if (i16 < 10) {
                const int kk = i16 * 4 + 960;
                const float4 wv = *reinterpret_cast<const float4*>(wr + kk);
                const float4 hv = *reinterpret_cast<const float4*>(&h_s[kk]);
                a3 += fmaf(wv.x, hv.x, fmaf(wv.y, hv.y, fmaf(wv.z, hv.z, wv.w * hv.w)));
            }
            const float* wrx = wb_x + (size_t)e * IN_SZ;
            #pragma unroll
            for (int m = 0; m < 9; ++m) {
                const int kk = i16 * 4 + m * 64;
                const float4 wv = *reinterpret_cast<const float4*>(wrx + kk);
                const float4 hv = *reinterpret_cast<const float4*>(&x_s[kk]);
                const float s = fmaf(wv.x, hv.x, fmaf(wv.y, hv.y, fmaf(wv.z, hv.z, wv.w * hv.w)));
                if ((m & 3) == 0) a0 += s; else if ((m & 3) == 1) a1 += s;
                else if ((m & 3) == 2) a2 += s; else a3 += s;
            }
            if (i16 < 11) {
                const int kk = i16 * 4 + 576;
                const float4 wv = *reinterpret_cast<const float4*>(wrx + kk);
                const float4 hv = *reinterpret_cast<const float4*>(&x_s[kk]);
                a3 += fmaf(wv.x, hv.x, fmaf(wv.y, hv.y, fmaf(wv.z, hv.z, wv.w * hv.w)));
            }
            float acc = (a0 + a1) + (a2 + a3);
            acc += __shfl_xor(acc, 1);
            acc += __shfl_xor(acc, 2);
            acc += __shfl_xor(acc, 4);
            acc += __shfl_xor(acc, 8);
            if (i16 == 0) pre[wave][e] = acc;
        }
        __syncthreads();

        if (wave == 0 && lane < EP_LEG) {
            const float gi = pre[0][lane] + bsum[0];
            const float gf = pre[1][lane] + bsum[1];
            const float gg = pre[2][lane] + bsum[2];
            const float go = pre[3][lane] + bsum[3];
            const float iv = sigm(gi);
            const float fv = sigm(gf);
            const float gv = tanh_fast(gg);
            const float ov = sigm(go);
            c_reg = fv * c_reg + iv * gv;
            const float h = ov * tanh_fast(c_reg);
            out[(size_t)t * HID + e0 + lane] = h;
            __hip_atomic_store(&hbuf[(t & 1) * 1024 + e0 + lane], h,
                               __ATOMIC_RELAXED, __HIP_MEMORY_SCOPE_AGENT);
        }
        if (++t >= T) break;
        if (wave == 0 && lane == 0) {
            asm volatile("s_waitcnt vmcnt(0)" ::: "memory");
            __hip_atomic_store(&flags[w], (unsigned)t,
                               __ATOMIC_RELAXED, __HIP_MEMORY_SCOPE_AGENT);
        }
        if (wave > 0) {
            if (lane < NW_LEG) {
                while (__hip_atomic_load(&flags[lane], __ATOMIC_RELAXED,
                                         __HIP_MEMORY_SCOPE_AGENT) < (unsigned)t) {}
            }
            const int rb = tid - 64;
            for (int i = rb; i < HID; i += 192) {
                h_s[i] = __hip_atomic_load(&hbuf[((t - 1) & 1) * 1024 + i],
                                           __ATOMIC_RELAXED, __HIP_MEMORY_SCOPE_AGENT);
            }
            for (int i = rb; i < IN_SZ; i += 192) x_s[i] = x[(size_t)t * IN_SZ + i];
        }
        __syncthreads();
    }
}

// ---------------- launch ----------------
extern "C" void kernel_launch(void* const* d_in, const int* in_sizes, int n_in,
                              void* d_out, int out_size, void* d_ws, size_t ws_size,
                              hipStream_t stream)
{
    const float* x   = (const float*)d_in[0];
    const float* Wih = (const float*)d_in[1];
    const float* Whh = (const float*)d_in[2];
    const float* bih = (const float*)d_in[3];
    const float* bhh = (const float*)d_in[4];
    float* out = (float*)d_out;
    const int T = in_sizes[0] / IN_SZ;

    char* ws = (char*)d_ws;
    unsigned* hb_u  = (unsigned*)ws;           // 2*1024 u32 = 8 KB (stamped h)
    unsigned* flags = (unsigned*)(ws + 8192);  // legacy only
    const size_t CTRL = 16384;
    (void)hipMemsetAsync(d_ws, 0, CTRL, stream);  // zero stamps/flags every call

    const size_t need32 = CTRL + (size_t)T * G4 * sizeof(float);
    const size_t need16 = CTRL + (size_t)T * G4 * sizeof(__hip_bfloat16);

    dim3 g1((G4 + 127) / 128, (T + 127) / 128), b1(256);

    if (ws_size >= need32) {
        float* xgbuf = (float*)(ws + CTRL);
        xg_gemm2<float><<<g1, b1, 0, stream>>>(x, Wih, bih, bhh, xgbuf, T);
        lstm_fast4<0><<<dim3(NWF), dim3(320), 0, stream>>>(xgbuf, Whh, out, hb_u, T);
    } else if (ws_size >= need16) {
        __hip_bfloat16* xgbuf = (__hip_bfloat16*)(ws + CTRL);
        xg_gemm2<__hip_bfloat16><<<g1, b1, 0, stream>>>(x, Wih, bih, bhh, xgbuf, T);
        lstm_fast4<1><<<dim3(NWF), dim3(320), 0, stream>>>(xgbuf, Whh, out, hb_u, T);
    } else {
        lstm_seq_legacy<<<dim3(NW_LEG), dim3(256), 0, stream>>>(
            x, Wih, Whh, bih, bhh, out, (float*)hb_u, flags, T);
    }
}

// Round 9
// 37976.685 us; speedup vs baseline: 1.0119x; 1.0119x over previous
//
#include <hip/hip_runtime.h>
#include <hip/hip_bf16.h>

// LSTM T=8192, I=620, H=1000, batch=1.
// Phase 1: xgT[t][e*4+g] = x[t] @ W_ih^T + b   (GEMM -> ws, transposed layout)
// Phase 2: 125 WGs x 384 threads = 4 producer waves + 1 gather wave + 1 xg wave.
//   Producer wave v owns h elems {w*8+2v, +1} end-to-end: dot (8 rows x 1000,
//   weights in regs) -> in-wave shfl reduce -> gates -> lane0 publishes both
//   h via global_atomic_swap_x2 (2 LSB mantissa stamp = (t+1)&3), NO drain.
//   Wave 4 (gatherer): vmcnt contains ONLY gather loads; one asm block per
//   attempt (4 loads + vmcnt(0) + outputs together -> no reorder hazard).
//   Wave 5 (xg loader): streams xgT into a 2-deep LDS ring; its HBM latency
//   never touches anyone else's vmcnt. One barrier per step.

#define IN_SZ   620
#define HID     1000
#define G4      4000
#define NWF     125
#define NW_LEG  50
#define EP_LEG  20

__device__ __forceinline__ float sigm(float v)      { return 1.0f / (1.0f + __expf(-v)); }
__device__ __forceinline__ float tanh_fast(float v) { return 2.0f / (1.0f + __expf(-2.0f * v)) - 1.0f; }

__device__ __forceinline__ void stxg_(float* p, float v) { *p = v; }
__device__ __forceinline__ void stxg_(__hip_bfloat16* p, float v) { *p = __float2bfloat16(v); }

// ---------------- Phase 1: xg GEMM, 128x128x16 tiles, 8x8 micro-tile ----------------
// Stores TRANSPOSED: xgT[m*4000 + e*4 + g]  (n = g*1000 + e)
template <typename XG>
__global__ __launch_bounds__(256) void xg_gemm2(
    const float* __restrict__ x,    // (T, 620)
    const float* __restrict__ Wih,  // (4000, 620)
    const float* __restrict__ bih,
    const float* __restrict__ bhh,
    XG* __restrict__ xg,            // (T, 4000) transposed-inner
    int T)
{
    constexpr int BM = 128, BN = 128, BK = 16, LDT = BM + 4;
    __shared__ float As[BK][LDT];
    __shared__ float Bs[BK][LDT];
    const int tid = threadIdx.x;
    const int tx = tid & 15, ty = tid >> 4;
    const int m0 = blockIdx.y * BM, n0 = blockIdx.x * BN;
    float acc[8][8] = {};

    for (int k0 = 0; k0 < IN_SZ; k0 += BK) {
        #pragma unroll
        for (int it = 0; it < 2; ++it) {
            const int r = (tid >> 2) + it * 64;
            const int c = (tid & 3) * 4;
            const int gk = k0 + c;
            {
                const int gm = m0 + r;
                float4 v = {0.f, 0.f, 0.f, 0.f};
                if (gm < T) {
                    if (gk + 3 < IN_SZ) {
                        v = *reinterpret_cast<const float4*>(x + (size_t)gm * IN_SZ + gk);
                    } else {
                        const float* row = x + (size_t)gm * IN_SZ;
                        v.x = (gk + 0 < IN_SZ) ? row[gk + 0] : 0.f;
                        v.y = (gk + 1 < IN_SZ) ? row[gk + 1] : 0.f;
                        v.z = (gk + 2 < IN_SZ) ? row[gk + 2] : 0.f;
                        v.w = (gk + 3 < IN_SZ) ? row[gk + 3] : 0.f;
                    }
                }
                As[c + 0][r] = v.x; As[c + 1][r] = v.y;
                As[c + 2][r] = v.z; As[c + 3][r] = v.w;
            }
            {
                const int gn = n0 + r;
                float4 v = {0.f, 0.f, 0.f, 0.f};
                if (gn < G4) {
                    if (gk + 3 < IN_SZ) {
                        v = *reinterpret_cast<const float4*>(Wih + (size_t)gn * IN_SZ + gk);
                    } else {
                        const float* row = Wih + (size_t)gn * IN_SZ;
                        v.x = (gk + 0 < IN_SZ) ? row[gk + 0] : 0.f;
                        v.y = (gk + 1 < IN_SZ) ? row[gk + 1] : 0.f;
                        v.z = (gk + 2 < IN_SZ) ? row[gk + 2] : 0.f;
                        v.w = (gk + 3 < IN_SZ) ? row[gk + 3] : 0.f;
                    }
                }
                Bs[c + 0][r] = v.x; Bs[c + 1][r] = v.y;
                Bs[c + 2][r] = v.z; Bs[c + 3][r] = v.w;
            }
        }
        __syncthreads();
        #pragma unroll
        for (int k = 0; k < BK; ++k) {
            float a[8], b[8];
            *reinterpret_cast<float4*>(&a[0]) = *reinterpret_cast<const float4*>(&As[k][ty * 8]);
            *reinterpret_cast<float4*>(&a[4]) = *reinterpret_cast<const float4*>(&As[k][ty * 8 + 4]);
            *reinterpret_cast<float4*>(&b[0]) = *reinterpret_cast<const float4*>(&Bs[k][tx * 8]);
            *reinterpret_cast<float4*>(&b[4]) = *reinterpret_cast<const float4*>(&Bs[k][tx * 8 + 4]);
            #pragma unroll
            for (int i = 0; i < 8; ++i)
                #pragma unroll
                for (int j = 0; j < 8; ++j)
                    acc[i][j] = fmaf(a[i], b[j], acc[i][j]);
        }
        __syncthreads();
    }

    float bias[8];
    #pragma unroll
    for (int j = 0; j < 8; ++j) {
        const int n = n0 + tx * 8 + j;
        bias[j] = (n < G4) ? (bih[n] + bhh[n]) : 0.f;
    }
    #pragma unroll
    for (int i = 0; i < 8; ++i) {
        const int m = m0 + ty * 8 + i;
        if (m >= T) continue;
        #pragma unroll
        for (int j = 0; j < 8; ++j) {
            const int n = n0 + tx * 8 + j;
            if (n < G4) {
                const int g = n / 1000, e = n - g * 1000;
                stxg_(&xg[(size_t)m * G4 + e * 4 + g], acc[i][j] + bias[j]);
            }
        }
    }
}

// ---------------- Phase 2 ----------------
template <int MODE>
__device__ __forceinline__ float ldxg(const void* xg_v, size_t idx) {
    if (MODE == 0) return ((const float*)xg_v)[idx];
    return __bfloat162float(((const __hip_bfloat16*)xg_v)[idx]);
}

template <int MODE>
__global__ __launch_bounds__(384, 1) void lstm_fast5(
    const void* __restrict__ xg_v,   // xgT (T,4000) [e*4+g]
    const float* __restrict__ Whh,   // (4000, 1000)
    float* __restrict__ out,         // (T, 1000)
    unsigned* hb_u,                  // 2 * 1024 u32 (double-buffered, stamped)
    int T)
{
    __shared__ __align__(16) unsigned hs[2][1024];
    __shared__ float xr_s[2][32];    // xg ring (2-deep)

    const int w = blockIdx.x, tid = threadIdx.x;
    const int wave = tid >> 6, lane = tid & 63;

    for (int i = tid; i < 2048; i += 384) ((unsigned*)hs)[i] = 0u;
    if (wave == 5 && lane < 32)      // prefill ring slot 0 (step 0)
        xr_s[0][lane] = ldxg<MODE>(xg_v, (size_t)w * 32 + lane);
    __syncthreads();

    // ---- producer lane roles ----
    const int e  = lane >> 5;          // elem parity (0/1)
    const int p  = (lane >> 3) & 3;    // gate
    const int k  = lane & 7;           // column-slice index within row
    const int we0w = w * 8 + wave * 2; // wave's 2 global h indices (waves 0-3)

    // ---- weight preload (waves 0-3): row (p*HID + we0w + e) ----
    float4 wreg[32];
    if (wave < 4) {
        const int gr = p * HID + we0w + e;
        const float* wrow = Whh + (size_t)gr * HID;
        #pragma unroll
        for (int m = 0; m < 31; ++m)
            wreg[m] = *reinterpret_cast<const float4*>(wrow + (k + 8 * m) * 4);
        wreg[31] = (k < 2) ? *reinterpret_cast<const float4*>(wrow + (k + 248) * 4)
                           : float4{0.f, 0.f, 0.f, 0.f};
    }
    const int tail_c = (k < 2) ? (k + 248) : k;

    float c_reg = 0.0f;                // lanes 0/32 of producer waves

    // xg-loader state: xg for step t+1, loaded one step ahead
    float xnext = 0.f;
    if (wave == 5 && lane < 32 && 1 < T)
        xnext = ldxg<MODE>(xg_v, (size_t)1 * G4 + w * 32 + lane);

    for (int t = 0;;) {
        if (wave < 4) {
            // ================= producers =================
            const float* hsf = reinterpret_cast<const float*>(&hs[t & 1][0]);
            float a0 = 0.f, a1 = 0.f, a2 = 0.f, a3 = 0.f;
            #pragma unroll
            for (int m = 0; m < 31; ++m) {
                const float4 hv = *reinterpret_cast<const float4*>(hsf + (k + 8 * m) * 4);
                const float s = fmaf(wreg[m].x, hv.x, fmaf(wreg[m].y, hv.y,
                                fmaf(wreg[m].z, hv.z, wreg[m].w * hv.w)));
                if ((m & 3) == 0) a0 += s; else if ((m & 3) == 1) a1 += s;
                else if ((m & 3) == 2) a2 += s; else a3 += s;
            }
            {
                const float4 hv = *reinterpret_cast<const float4*>(hsf + tail_c * 4);
                a3 += fmaf(wreg[31].x, hv.x, fmaf(wreg[31].y, hv.y,
                      fmaf(wreg[31].z, hv.z, wreg[31].w * hv.w)));
            }
            float acc = (a0 + a1) + (a2 + a3);
            acc += __shfl_xor(acc, 1);
            acc += __shfl_xor(acc, 2);
            acc += __shfl_xor(acc, 4);   // all 8 lanes of the row hold the sum

            // lane base+q (q<4) takes (elem e, gate q)
            const float gsumv = __shfl(acc, (lane & 32) + (lane & 3) * 8);
            const float xv = xr_s[t & 1][(wave * 2 + e) * 4 + (lane & 3)];
            const float gg = gsumv + xv;
            const float actv = ((lane & 3) == 2) ? tanh_fast(gg) : sigm(gg);

            const int base = lane & 32;
            const float iv = __shfl(actv, base + 0);
            const float fv = __shfl(actv, base + 1);
            const float gv = __shfl(actv, base + 2);
            const float ov = __shfl(actv, base + 3);
            float hval = 0.f;
            if ((lane & 31) == 0) {
                c_reg = fv * c_reg + iv * gv;
                hval = ov * tanh_fast(c_reg);
            }
            const float h1 = __shfl(hval, 32);
            if (lane == 0) {
                const unsigned st = (unsigned)((t + 1) & 3);
                const unsigned u0 = (__float_as_uint(hval) & ~3u) | st;
                const unsigned u1 = (__float_as_uint(h1)   & ~3u) | st;
                const unsigned long long dat =
                    (unsigned long long)u0 | ((unsigned long long)u1 << 32);
                const unsigned long long addr =
                    (unsigned long long)(uintptr_t)(hb_u + (t & 1) * 1024 + we0w);
                asm volatile("global_atomic_swap_x2 %0, %1, off"
                             :: "v"(addr), "v"(dat) : "memory");
                float2 o2; o2.x = hval; o2.y = h1;
                *reinterpret_cast<float2*>(out + (size_t)t * HID + we0w) = o2;
                // no drain: ack retires in background
            }
        } else if (wave == 4) {
            // ================= gatherer (clean vmcnt) =================
            if (t + 1 < T) {
                const unsigned want = (unsigned)(t + 1) & 3u;
                const uint4* srcb =
                    reinterpret_cast<const uint4*>(hb_u + (t & 1) * 1024);
                const bool has3 = (192 + lane) < 250;
                const uint4* p0 = srcb + lane;
                const uint4* p1 = srcb + 64 + lane;
                const uint4* p2 = srcb + 128 + lane;
                const uint4* p3 = srcb + (has3 ? 192 + lane : 0);
                uint4 v0, v1, v2, v3;
                for (;;) {
                    asm volatile(
                        "global_load_dwordx4 %0, %4, off sc0 sc1\n\t"
                        "global_load_dwordx4 %1, %5, off sc0 sc1\n\t"
                        "global_load_dwordx4 %2, %6, off sc0 sc1\n\t"
                        "global_load_dwordx4 %3, %7, off sc0 sc1\n\t"
                        "s_waitcnt vmcnt(0)"
                        : "=&v"(v0), "=&v"(v1), "=&v"(v2), "=&v"(v3)
                        : "v"(p0), "v"(p1), "v"(p2), "v"(p3)
                        : "memory");
                    unsigned bad =
                        ((v0.x ^ want) | (v0.y ^ want) | (v0.z ^ want) | (v0.w ^ want) |
                         (v1.x ^ want) | (v1.y ^ want) | (v1.z ^ want) | (v1.w ^ want) |
                         (v2.x ^ want) | (v2.y ^ want) | (v2.z ^ want) | (v2.w ^ want)) & 3u;
                    if (has3)
                        bad |= ((v3.x ^ want) | (v3.y ^ want) |
                                (v3.z ^ want) | (v3.w ^ want)) & 3u;
                    if (bad == 0u) break;
                }
                uint4* dst = reinterpret_cast<uint4*>(&hs[(t + 1) & 1][0]);
                dst[lane] = v0;
                dst[64 + lane] = v1;
                dst[128 + lane] = v2;
                if (has3) dst[192 + lane] = v3;
            }
        } else {
            // ================= xg loader =================
            if (lane < 32 && t + 1 < T) {
                xr_s[(t + 1) & 1][lane] = xnext;   // compiler waits this load
                if (t + 2 < T)
                    xnext = ldxg<MODE>(xg_v, (size_t)(t + 2) * G4 + w * 32 + lane);
            }
        }

        if (++t >= T) break;
        __syncthreads();   // joins producer publish epoch & gather/xg fill
    }
}

// ---------------- legacy fallback (tiny ws): fused x-projection ----------------
__global__ __launch_bounds__(256, 1) void lstm_seq_legacy(
    const float* __restrict__ x,
    const float* __restrict__ Wih,
    const float* __restrict__ Whh,
    const float* __restrict__ bih,
    const float* __restrict__ bhh,
    float* __restrict__ out,
    float* hbuf, unsigned* flags, int T)
{
    __shared__ __align__(16) float h_s[HID];
    __shared__ __align__(16) float x_s[IN_SZ + 4];
    __shared__ float pre[4][EP_LEG];

    const int w = blockIdx.x, tid = threadIdx.x;
    const int wave = tid >> 6, lane = tid & 63;
    const int i16 = lane & 15, p = lane >> 4;
    const int e0 = w * EP_LEG;

    for (int i = tid; i < HID; i += 256) h_s[i] = 0.0f;
    for (int i = tid; i < IN_SZ; i += 256) x_s[i] = x[i];
    __syncthreads();

    const float* wb_h = Whh + ((size_t)wave * HID + e0) * HID;
    const float* wb_x = Wih + ((size_t)wave * HID + e0) * IN_SZ;
    float c_reg = 0.0f;
    float bsum[4] = {0.f, 0.f, 0.f, 0.f};
    if (wave == 0 && lane < EP_LEG) {
        #pragma unroll
        for (int g = 0; g < 4; ++g) {
            int n = g * HID + e0 + lane;
            bsum[g] = bih[n] + bhh[n];
        }
    }

    for (int t = 0;;) {
        #pragma unroll
        for (int pass = 0; pass < EP_LEG / 4; ++pass) {
            const int e = pass * 4 + p;
            const float* wr = wb_h + (size_t)e * HID;
            float a0 = 0.f, a1 = 0.f, a2 = 0.f, a3 = 0.f;
            #pragma unroll
            for (int m = 0; m < 15; ++m) {
                const int kk = i16 * 4 + m * 64;
                const float4 wv = *reinterpret_cast<const float4*>(wr + kk);
                const float4 hv = *reinterpret_cast<const float4*>(&h_s[kk]);
                const float s = fmaf(wv.x, hv.x, fmaf(wv.y, hv.y, fmaf(wv.z, hv.z, wv.w * hv.w)));
                if ((m & 3) == 0) a0 += s; else if ((m & 3) == 1) a1 += s;
                else if ((m & 3) == 2) a2 += s; else a3 += s;
            }
            if (i16 < 10) {
                const int kk = i16 * 4 + 960;
                const float4 wv = *reinterpret_cast<const float4*>(wr + kk);
                const float4 hv = *reinterpret_cast<const float4*>(&h_s[kk]);
                a3 += fmaf(wv.x, hv.x, fmaf(wv.y, hv.y, fmaf(wv.z, hv.z, wv.w * hv.w)));
            }
            const float* wrx = wb_x + (size_t)e * IN_SZ;
            #pragma unroll
            for (int m = 0; m < 9; ++m) {
                const int kk = i16 * 4 + m * 64;
                const float4 wv = *reinterpret_cast<const float4*>(wrx + kk);
                const float4 hv = *reinterpret_cast<const float4*>(&x_s[kk]);
                const float s = fmaf(wv.x, hv.x, fmaf(wv.y, hv.y, fmaf(wv.z, hv.z, wv.w * hv.w)));
                if ((m & 3) == 0) a0 += s; else if ((m & 3) == 1) a1 += s;
                else if ((m & 3) == 2) a2 += s; else a3 += s;
            }
            if (i16 < 11) {
                const int kk = i16 * 4 + 576;
                const float4 wv = *reinterpret_cast<const float4*>(wrx + kk);
                const float4 hv = *reinterpret_cast<const float4*>(&x_s[kk]);
                a3 += fmaf(wv.x, hv.x, fmaf(wv.y, hv.y, fmaf(wv.z, hv.z, wv.w * hv.w)));
            }
            float acc = (a0 + a1) + (a2 + a3);
            acc += __shfl_xor(acc, 1);
            acc += __shfl_xor(acc, 2);
            acc += __shfl_xor(acc, 4);
            acc += __shfl_xor(acc, 8);
            if (i16 == 0) pre[wave][e] = acc;
        }
        __syncthreads();

        if (wave == 0 && lane < EP_LEG) {
            const float gi = pre[0][lane] + bsum[0];
            const float gf = pre[1][lane] + bsum[1];
            const float gg = pre[2][lane] + bsum[2];
            const float go = pre[3][lane] + bsum[3];
            const float iv = sigm(gi);
            const float fv = sigm(gf);
            const float gv = tanh_fast(gg);
            const float ov = sigm(go);
            c_reg = fv * c_reg + iv * gv;
            const float h = ov * tanh_fast(c_reg);
            out[(size_t)t * HID + e0 + lane] = h;
            __hip_atomic_store(&hbuf[(t & 1) * 1024 + e0 + lane], h,
                               __ATOMIC_RELAXED, __HIP_MEMORY_SCOPE_AGENT);
        }
        if (++t >= T) break;
        if (wave == 0 && lane == 0) {
            asm volatile("s_waitcnt vmcnt(0)" ::: "memory");
            __hip_atomic_store(&flags[w], (unsigned)t,
                               __ATOMIC_RELAXED, __HIP_MEMORY_SCOPE_AGENT);
        }
        if (wave > 0) {
            if (lane < NW_LEG) {
                while (__hip_atomic_load(&flags[lane], __ATOMIC_RELAXED,
                                         __HIP_MEMORY_SCOPE_AGENT) < (unsigned)t) {}
            }
            const int rb = tid - 64;
            for (int i = rb; i < HID; i += 192) {
                h_s[i] = __hip_atomic_load(&hbuf[((t - 1) & 1) * 1024 + i],
                                           __ATOMIC_RELAXED, __HIP_MEMORY_SCOPE_AGENT);
            }
            for (int i = rb; i < IN_SZ; i += 192) x_s[i] = x[(size_t)t * IN_SZ + i];
        }
        __syncthreads();
    }
}

// ---------------- launch ----------------
extern "C" void kernel_launch(void* const* d_in, const int* in_sizes, int n_in,
                              void* d_out, int out_size, void* d_ws, size_t ws_size,
                              hipStream_t stream)
{
    const float* x   = (const float*)d_in[0];
    const float* Wih = (const float*)d_in[1];
    const float* Whh = (const float*)d_in[2];
    const float* bih = (const float*)d_in[3];
    const float* bhh = (const float*)d_in[4];
    float* out = (float*)d_out;
    const int T = in_sizes[0] / IN_SZ;

    char* ws = (char*)d_ws;
    unsigned* hb_u  = (unsigned*)ws;           // 2*1024 u32 = 8 KB (stamped h)
    unsigned* flags = (unsigned*)(ws + 8192);  // legacy only
    const size_t CTRL = 16384;
    (void)hipMemsetAsync(d_ws, 0, CTRL, stream);  // zero stamps/flags every call

    const size_t need32 = CTRL + (size_t)T * G4 * sizeof(float);
    const size_t need16 = CTRL + (size_t)T * G4 * sizeof(__hip_bfloat16);

    dim3 g1((G4 + 127) / 128, (T + 127) / 128), b1(256);

    if (ws_size >= need32) {
        float* xgbuf = (float*)(ws + CTRL);
        xg_gemm2<float><<<g1, b1, 0, stream>>>(x, Wih, bih, bhh, xgbuf, T);
        lstm_fast5<0><<<dim3(NWF), dim3(384), 0, stream>>>(xgbuf, Whh, out, hb_u, T);
    } else if (ws_size >= need16) {
        __hip_bfloat16* xgbuf = (__hip_bfloat16*)(ws + CTRL);
        xg_gemm2<__hip_bfloat16><<<g1, b1, 0, stream>>>(x, Wih, bih, bhh, xgbuf, T);
        lstm_fast5<1><<<dim3(NWF), dim3(384), 0, stream>>>(xgbuf, Whh, out, hb_u, T);
    } else {
        lstm_seq_legacy<<<dim3(NW_LEG), dim3(256), 0, stream>>>(
            x, Wih, Whh, bih, bhh, out, (float*)hb_u, flags, T);
    }
}

// Round 10
// 19851.587 us; speedup vs baseline: 1.9358x; 1.9130x over previous
//
#include <hip/hip_runtime.h>
#include <hip/hip_bf16.h>

// LSTM T=8192, I=620, H=1000, batch=1.
// Phase 1: xgT[t][e*4+g] = x[t] @ W_ih^T + b   (GEMM -> ws, transposed layout)
// Phase 2 (R4 structure restored): 125 WGs x 256 threads. W_hh in registers
//   (2 rows/lane). Per step: all waves dot -> gsum; bar1; wave0 finalizes
//   gates (1 activation/lane over 32 lanes, shfl combine), publishes stamped
//   h (2 LSB mantissa = (t+1)&3) via sc0sc1 write-through stores, prefetches
//   next xg (contiguous 128B, transposed layout); waves 1-3 retry-gather
//   stamped h with clean vmcnt (one asm block per attempt); bar2.
//   Delta vs R4: transposed xg (no over-fetch), dup-free gather tail.

#define IN_SZ   620
#define HID     1000
#define G4      4000
#define NWF     125
#define NW_LEG  50
#define EP_LEG  20

__device__ __forceinline__ float sigm(float v)      { return 1.0f / (1.0f + __expf(-v)); }
__device__ __forceinline__ float tanh_fast(float v) { return 2.0f / (1.0f + __expf(-2.0f * v)) - 1.0f; }

__device__ __forceinline__ void stxg_(float* p, float v) { *p = v; }
__device__ __forceinline__ void stxg_(__hip_bfloat16* p, float v) { *p = __float2bfloat16(v); }

// ---------------- Phase 1: xg GEMM, 128x128x16 tiles, 8x8 micro-tile ----------------
// Stores TRANSPOSED: xgT[m*4000 + e*4 + g]  (n = g*1000 + e)
template <typename XG>
__global__ __launch_bounds__(256) void xg_gemm2(
    const float* __restrict__ x,    // (T, 620)
    const float* __restrict__ Wih,  // (4000, 620)
    const float* __restrict__ bih,
    const float* __restrict__ bhh,
    XG* __restrict__ xg,            // (T, 4000) transposed-inner
    int T)
{
    constexpr int BM = 128, BN = 128, BK = 16, LDT = BM + 4;
    __shared__ float As[BK][LDT];
    __shared__ float Bs[BK][LDT];
    const int tid = threadIdx.x;
    const int tx = tid & 15, ty = tid >> 4;
    const int m0 = blockIdx.y * BM, n0 = blockIdx.x * BN;
    float acc[8][8] = {};

    for (int k0 = 0; k0 < IN_SZ; k0 += BK) {
        #pragma unroll
        for (int it = 0; it < 2; ++it) {
            const int r = (tid >> 2) + it * 64;
            const int c = (tid & 3) * 4;
            const int gk = k0 + c;
            {
                const int gm = m0 + r;
                float4 v = {0.f, 0.f, 0.f, 0.f};
                if (gm < T) {
                    if (gk + 3 < IN_SZ) {
                        v = *reinterpret_cast<const float4*>(x + (size_t)gm * IN_SZ + gk);
                    } else {
                        const float* row = x + (size_t)gm * IN_SZ;
                        v.x = (gk + 0 < IN_SZ) ? row[gk + 0] : 0.f;
                        v.y = (gk + 1 < IN_SZ) ? row[gk + 1] : 0.f;
                        v.z = (gk + 2 < IN_SZ) ? row[gk + 2] : 0.f;
                        v.w = (gk + 3 < IN_SZ) ? row[gk + 3] : 0.f;
                    }
                }
                As[c + 0][r] = v.x; As[c + 1][r] = v.y;
                As[c + 2][r] = v.z; As[c + 3][r] = v.w;
            }
            {
                const int gn = n0 + r;
                float4 v = {0.f, 0.f, 0.f, 0.f};
                if (gn < G4) {
                    if (gk + 3 < IN_SZ) {
                        v = *reinterpret_cast<const float4*>(Wih + (size_t)gn * IN_SZ + gk);
                    } else {
                        const float* row = Wih + (size_t)gn * IN_SZ;
                        v.x = (gk + 0 < IN_SZ) ? row[gk + 0] : 0.f;
                        v.y = (gk + 1 < IN_SZ) ? row[gk + 1] : 0.f;
                        v.z = (gk + 2 < IN_SZ) ? row[gk + 2] : 0.f;
                        v.w = (gk + 3 < IN_SZ) ? row[gk + 3] : 0.f;
                    }
                }
                Bs[c + 0][r] = v.x; Bs[c + 1][r] = v.y;
                Bs[c + 2][r] = v.z; Bs[c + 3][r] = v.w;
            }
        }
        __syncthreads();
        #pragma unroll
        for (int k = 0; k < BK; ++k) {
            float a[8], b[8];
            *reinterpret_cast<float4*>(&a[0]) = *reinterpret_cast<const float4*>(&As[k][ty * 8]);
            *reinterpret_cast<float4*>(&a[4]) = *reinterpret_cast<const float4*>(&As[k][ty * 8 + 4]);
            *reinterpret_cast<float4*>(&b[0]) = *reinterpret_cast<const float4*>(&Bs[k][tx * 8]);
            *reinterpret_cast<float4*>(&b[4]) = *reinterpret_cast<const float4*>(&Bs[k][tx * 8 + 4]);
            #pragma unroll
            for (int i = 0; i < 8; ++i)
                #pragma unroll
                for (int j = 0; j < 8; ++j)
                    acc[i][j] = fmaf(a[i], b[j], acc[i][j]);
        }
        __syncthreads();
    }

    float bias[8];
    #pragma unroll
    for (int j = 0; j < 8; ++j) {
        const int n = n0 + tx * 8 + j;
        bias[j] = (n < G4) ? (bih[n] + bhh[n]) : 0.f;
    }
    #pragma unroll
    for (int i = 0; i < 8; ++i) {
        const int m = m0 + ty * 8 + i;
        if (m >= T) continue;
        #pragma unroll
        for (int j = 0; j < 8; ++j) {
            const int n = n0 + tx * 8 + j;
            if (n < G4) {
                const int g = n / 1000, e = n - g * 1000;
                stxg_(&xg[(size_t)m * G4 + e * 4 + g], acc[i][j] + bias[j]);
            }
        }
    }
}

// ---------------- Phase 2: register-resident recurrent kernel (R4 structure) ----------------
template <int MODE>
__device__ __forceinline__ float ldxg(const void* xg_v, size_t idx) {
    if (MODE == 0) return ((const float*)xg_v)[idx];
    return __bfloat162float(((const __hip_bfloat16*)xg_v)[idx]);
}

template <int MODE>
__global__ __launch_bounds__(256, 1) void lstm_fast(
    const void* __restrict__ xg_v,   // xgT (T,4000) [e*4+g]
    const float* __restrict__ Whh,   // (4000, 1000)
    float* __restrict__ out,         // (T, 1000)
    unsigned* hb_u,                  // 2 * 1024 u32 (double-buffered, stamped)
    int T)
{
    __shared__ __align__(16) unsigned hs[2][1024];
    __shared__ float gsum[4][4][2];  // [src wave][gate][elem parity]

    const int w = blockIdx.x, tid = threadIdx.x;
    const int wave = tid >> 6, lane = tid & 63;
    const int i16 = lane & 15, p = lane >> 4;       // p = gate for the dot
    const int we0 = w * 8 + wave * 2;               // this wave's 2 h-elements

    for (int i = tid; i < 2048; i += 256) ((unsigned*)hs)[i] = 0u;
    __syncthreads();

    // ---- weight preload into registers: rows (p*HID + we0), (.. + 1) ----
    const size_t rowA = (size_t)(p * HID + we0) * HID;
    const size_t rowB = rowA + HID;
    float4 wA[16], wB[16], hreg[16];
    #pragma unroll
    for (int m = 0; m < 15; ++m) {
        wA[m] = *reinterpret_cast<const float4*>(Whh + rowA + i16 * 4 + m * 64);
        wB[m] = *reinterpret_cast<const float4*>(Whh + rowB + i16 * 4 + m * 64);
    }
    if (i16 < 10) {
        wA[15] = *reinterpret_cast<const float4*>(Whh + rowA + 960 + i16 * 4);
        wB[15] = *reinterpret_cast<const float4*>(Whh + rowB + 960 + i16 * 4);
    } else {
        wA[15] = float4{0.f, 0.f, 0.f, 0.f};
        wB[15] = float4{0.f, 0.f, 0.f, 0.f};
    }

    // ---- wave-0 gate-lane mapping: lanes 0..31 ----
    const int gv_ = (lane >> 3) & 3;   // source wave v
    const int gp  = (lane >> 1) & 3;   // gate
    const int ge  = lane & 1;          // elem parity
    const int eg  = w * 8 + gv_ * 2 + ge;      // global h index for this lane
    const int xoff = (gv_ * 2 + ge) * 4 + gp;  // offset in WG's 32-dword xg slab
    const int shbase = (lane & ~7) | ge;       // owner-lane base for shfl combine
    float c_reg = 0.0f;                        // owner lanes (gp==0) of wave 0
    float xv = 0.0f;
    if (wave == 0 && lane < 32)
        xv = ldxg<MODE>(xg_v, (size_t)w * 32 + xoff);

    // ---- gather mapping (waves 1-3; 192 threads, dup-free tail) ----
    const int tid2 = tid - 64;                     // 0..191
    const int iA = tid2;
    const int iB = (tid2 < 58) ? (192 + tid2) : tid2;  // tail slots 192..249

    for (int t = 0;;) {
        const int rb = t & 1;

        // ---- h slice LDS -> regs ----
        #pragma unroll
        for (int m = 0; m < 15; ++m)
            hreg[m] = *reinterpret_cast<const float4*>(&hs[rb][i16 * 4 + m * 64]);
        hreg[15] = *reinterpret_cast<const float4*>(&hs[rb][960 + i16 * 4]);

        // ---- dot: 2 rows x 64 floats per lane ----
        float a0 = 0.f, a1 = 0.f, a2 = 0.f, a3 = 0.f;
        float b0 = 0.f, b1 = 0.f, b2 = 0.f, b3 = 0.f;
        #pragma unroll
        for (int m = 0; m < 16; ++m) {
            const float4 hv = hreg[m];
            const float sA = fmaf(wA[m].x, hv.x, fmaf(wA[m].y, hv.y,
                             fmaf(wA[m].z, hv.z, wA[m].w * hv.w)));
            const float sB = fmaf(wB[m].x, hv.x, fmaf(wB[m].y, hv.y,
                             fmaf(wB[m].z, hv.z, wB[m].w * hv.w)));
            if ((m & 3) == 0)      { a0 += sA; b0 += sB; }
            else if ((m & 3) == 1) { a1 += sA; b1 += sB; }
            else if ((m & 3) == 2) { a2 += sA; b2 += sB; }
            else                   { a3 += sA; b3 += sB; }
        }
        float rA = (a0 + a1) + (a2 + a3);
        float rB = (b0 + b1) + (b2 + b3);
        rA += __shfl_xor(rA, 1); rB += __shfl_xor(rB, 1);
        rA += __shfl_xor(rA, 2); rB += __shfl_xor(rB, 2);
        rA += __shfl_xor(rA, 4); rB += __shfl_xor(rB, 4);
        rA += __shfl_xor(rA, 8); rB += __shfl_xor(rB, 8);
        if (i16 == 0) { gsum[wave][p][0] = rA; gsum[wave][p][1] = rB; }
        __syncthreads();   // bar1: gsum complete, hs[rb] reads done

        // ---- wave 0: parallel gates, cell update, stamped publish ----
        if (wave == 0) {
            const float g = gsum[gv_][gp][ge] + xv;
            const float act = (gp == 2) ? tanh_fast(g) : sigm(g);
            const float iv = __shfl(act, shbase);
            const float fv = __shfl(act, shbase + 2);
            const float g2 = __shfl(act, shbase + 4);
            const float ov = __shfl(act, shbase + 6);
            if (lane < 32 && gp == 0) {    // owner lanes: v*8 + e
                c_reg = fv * c_reg + iv * g2;
                const float h = ov * tanh_fast(c_reg);
                out[(size_t)t * HID + eg] = h;
                const unsigned hb = (__float_as_uint(h) & ~3u) | (unsigned)((t + 1) & 3);
                // sc0sc1 write-through store: lands at the coherence point
                __hip_atomic_store(hb_u + rb * 1024 + eg, hb,
                                   __ATOMIC_RELAXED, __HIP_MEMORY_SCOPE_AGENT);
            }
            // xg prefetch for next step (contiguous 128B slab; only in wave 0's
            // vmcnt — gather waves never wait on it)
            if (lane < 32 && t + 1 < T)
                xv = ldxg<MODE>(xg_v, (size_t)(t + 1) * G4 + w * 32 + xoff);
        }

        if (++t >= T) break;

        // ---- waves 1-3: retry-gather stamped h with clean vmcnt ----
        if (wave > 0) {
            const unsigned want = (unsigned)t & 3u;        // stamp of h^{t-1}
            const uint4* srcb =
                reinterpret_cast<const uint4*>(hb_u + ((t - 1) & 1) * 1024);
            uint4 vA, vB;
            for (;;) {
                asm volatile("global_load_dwordx4 %0, %2, off sc0 sc1\n\t"
                             "global_load_dwordx4 %1, %3, off sc0 sc1\n\t"
                             "s_waitcnt vmcnt(0)"
                             : "=&v"(vA), "=&v"(vB)
                             : "v"(srcb + iA), "v"(srcb + iB)
                             : "memory");
                const unsigned bad =
                    ((vA.x ^ want) | (vA.y ^ want) | (vA.z ^ want) | (vA.w ^ want) |
                     (vB.x ^ want) | (vB.y ^ want) | (vB.z ^ want) | (vB.w ^ want)) & 3u;
                if (bad == 0u) break;
            }
            uint4* dst = reinterpret_cast<uint4*>(&hs[t & 1][0]);
            dst[iA] = vA;
            if (tid2 < 58) dst[iB] = vB;   // tail slots, no duplicate writes
        }
        __syncthreads();   // bar2: hs[t&1] ready
    }
}

// ---------------- legacy fallback (tiny ws): fused x-projection ----------------
__global__ __launch_bounds__(256, 1) void lstm_seq_legacy(
    const float* __restrict__ x,
    const float* __restrict__ Wih,
    const float* __restrict__ Whh,
    const float* __restrict__ bih,
    const float* __restrict__ bhh,
    float* __restrict__ out,
    float* hbuf, unsigned* flags, int T)
{
    __shared__ __align__(16) float h_s[HID];
    __shared__ __align__(16) float x_s[IN_SZ + 4];
    __shared__ float pre[4][EP_LEG];

    const int w = blockIdx.x, tid = threadIdx.x;
    const int wave = tid >> 6, lane = tid & 63;
    const int i16 = lane & 15, p = lane >> 4;
    const int e0 = w * EP_LEG;

    for (int i = tid; i < HID; i += 256) h_s[i] = 0.0f;
    for (int i = tid; i < IN_SZ; i += 256) x_s[i] = x[i];
    __syncthreads();

    const float* wb_h = Whh + ((size_t)wave * HID + e0) * HID;
    const float* wb_x = Wih + ((size_t)wave * HID + e0) * IN_SZ;
    float c_reg = 0.0f;
    float bsum[4] = {0.f, 0.f, 0.f, 0.f};
    if (wave == 0 && lane < EP_LEG) {
        #pragma unroll
        for (int g = 0; g < 4; ++g) {
            int n = g * HID + e0 + lane;
            bsum[g] = bih[n] + bhh[n];
        }
    }

    for (int t = 0;;) {
        #pragma unroll
        for (int pass = 0; pass < EP_LEG / 4; ++pass) {
            const int e = pass * 4 + p;
            const float* wr = wb_h + (size_t)e * HID;
            float a0 = 0.f, a1 = 0.f, a2 = 0.f, a3 = 0.f;
            #pragma unroll
            for (int m = 0; m < 15; ++m) {
                const int kk = i16 * 4 + m * 64;
                const float4 wv = *reinterpret_cast<const float4*>(wr + kk);
                const float4 hv = *reinterpret_cast<const float4*>(&h_s[kk]);
                const float s = fmaf(wv.x, hv.x, fmaf(wv.y, hv.y, fmaf(wv.z, hv.z, wv.w * hv.w)));
                if ((m & 3) == 0) a0 += s; else if ((m & 3) == 1) a1 += s;
                else if ((m & 3) == 2) a2 += s; else a3 += s;
            }
            if (i16 < 10) {
                const int kk = i16 * 4 + 960;
                const float4 wv = *reinterpret_cast<const float4*>(wr + kk);
                const float4 hv = *reinterpret_cast<const float4*>(&h_s[kk]);
                a3 += fmaf(wv.x, hv.x, fmaf(wv.y, hv.y, fmaf(wv.z, hv.z, wv.w * hv.w)));
            }
            const float* wrx = wb_x + (size_t)e * IN_SZ;
            #pragma unroll
            for (int m = 0; m < 9; ++m) {
                const int kk = i16 * 4 + m * 64;
                const float4 wv = *reinterpret_cast<const float4*>(wrx + kk);
                const float4 hv = *reinterpret_cast<const float4*>(&x_s[kk]);
                const float s = fmaf(wv.x, hv.x, fmaf(wv.y, hv.y, fmaf(wv.z, hv.z, wv.w * hv.w)));
                if ((m & 3) == 0) a0 += s; else if ((m & 3) == 1) a1 += s;
                else if ((m & 3) == 2) a2 += s; else a3 += s;
            }
            if (i16 < 11) {
                const int kk = i16 * 4 + 576;
                const float4 wv = *reinterpret_cast<const float4*>(wrx + kk);
                const float4 hv = *reinterpret_cast<const float4*>(&x_s[kk]);
                a3 += fmaf(wv.x, hv.x, fmaf(wv.y, hv.y, fmaf(wv.z, hv.z, wv.w * hv.w)));
            }
            float acc = (a0 + a1) + (a2 + a3);
            acc += __shfl_xor(acc, 1);
            acc += __shfl_xor(acc, 2);
            acc += __shfl_xor(acc, 4);
            acc += __shfl_xor(acc, 8);
            if (i16 == 0) pre[wave][e] = acc;
        }
        __syncthreads();

        if (wave == 0 && lane < EP_LEG) {
            const float gi = pre[0][lane] + bsum[0];
            const float gf = pre[1][lane] + bsum[1];
            const float gg = pre[2][lane] + bsum[2];
            const float go = pre[3][lane] + bsum[3];
            const float iv = sigm(gi);
            const float fv = sigm(gf);
            const float gv = tanh_fast(gg);
            const float ov = sigm(go);
            c_reg = fv * c_reg + iv * gv;
            const float h = ov * tanh_fast(c_reg);
            out[(size_t)t * HID + e0 + lane] = h;
            __hip_atomic_store(&hbuf[(t & 1) * 1024 + e0 + lane], h,
                               __ATOMIC_RELAXED, __HIP_MEMORY_SCOPE_AGENT);
        }
        if (++t >= T) break;
        if (wave == 0 && lane == 0) {
            asm volatile("s_waitcnt vmcnt(0)" ::: "memory");
            __hip_atomic_store(&flags[w], (unsigned)t,
                               __ATOMIC_RELAXED, __HIP_MEMORY_SCOPE_AGENT);
        }
        if (wave > 0) {
            if (lane < NW_LEG) {
                while (__hip_atomic_load(&flags[lane], __ATOMIC_RELAXED,
                                         __HIP_MEMORY_SCOPE_AGENT) < (unsigned)t) {}
            }
            const int rb = tid - 64;
            for (int i = rb; i < HID; i += 192) {
                h_s[i] = __hip_atomic_load(&hbuf[((t - 1) & 1) * 1024 + i],
                                           __ATOMIC_RELAXED, __HIP_MEMORY_SCOPE_AGENT);
            }
            for (int i = rb; i < IN_SZ; i += 192) x_s[i] = x[(size_t)t * IN_SZ + i];
        }
        __syncthreads();
    }
}

// ---------------- launch ----------------
extern "C" void kernel_launch(void* const* d_in, const int* in_sizes, int n_in,
                              void* d_out, int out_size, void* d_ws, size_t ws_size,
                              hipStream_t stream)
{
    const float* x   = (const float*)d_in[0];
    const float* Wih = (const float*)d_in[1];
    const float* Whh = (const float*)d_in[2];
    const float* bih = (const float*)d_in[3];
    const float* bhh = (const float*)d_in[4];
    float* out = (float*)d_out;
    const int T = in_sizes[0] / IN_SZ;

    char* ws = (char*)d_ws;
    unsigned* hb_u  = (unsigned*)ws;           // 2*1024 u32 = 8 KB (stamped h)
    unsigned* flags = (unsigned*)(ws + 8192);  // legacy only
    const size_t CTRL = 16384;
    (void)hipMemsetAsync(d_ws, 0, CTRL, stream);  // zero stamps/flags every call

    const size_t need32 = CTRL + (size_t)T * G4 * sizeof(float);
    const size_t need16 = CTRL + (size_t)T * G4 * sizeof(__hip_bfloat16);

    dim3 g1((G4 + 127) / 128, (T + 127) / 128), b1(256);

    if (ws_size >= need32) {
        float* xgbuf = (float*)(ws + CTRL);
        xg_gemm2<float><<<g1, b1, 0, stream>>>(x, Wih, bih, bhh, xgbuf, T);
        lstm_fast<0><<<dim3(NWF), dim3(256), 0, stream>>>(xgbuf, Whh, out, hb_u, T);
    } else if (ws_size >= need16) {
        __hip_bfloat16* xgbuf = (__hip_bfloat16*)(ws + CTRL);
        xg_gemm2<__hip_bfloat16><<<g1, b1, 0, stream>>>(x, Wih, bih, bhh, xgbuf, T);
        lstm_fast<1><<<dim3(NWF), dim3(256), 0, stream>>>(xgbuf, Whh, out, hb_u, T);
    } else {
        lstm_seq_legacy<<<dim3(NW_LEG), dim3(256), 0, stream>>>(
            x, Wih, Whh, bih, bhh, out, (float*)hb_u, flags, T);
    }
}

// Round 11
// 18828.217 us; speedup vs baseline: 2.0410x; 1.0544x over previous
//
#include <hip/hip_runtime.h>
#include <hip/hip_bf16.h>

// LSTM T=8192, I=620, H=1000, batch=1.
// Phase 1: xgT[t][e*4+g] = x[t] @ W_ih^T + b   (GEMM -> ws, transposed layout)
// Phase 2 (R10 structure, frozen): 125 WGs x 256 threads, W_hh in registers.
//   Per step: all waves dot -> gsum; bar1; wave0 gates + stamped sc0sc1
//   write-through publish (2 LSB mantissa = (t+1)&3) + xg prefetch;
//   waves 1-3 retry-gather stamped h (clean vmcnt, one asm block/attempt).
//   R11 delta: s_sleep(3) pre-gather (align first probe past publish
//   visibility), publish store before out store, xg load issued pre-gates.

#define IN_SZ   620
#define HID     1000
#define G4      4000
#define NWF     125
#define NW_LEG  50
#define EP_LEG  20

__device__ __forceinline__ float sigm(float v)      { return 1.0f / (1.0f + __expf(-v)); }
__device__ __forceinline__ float tanh_fast(float v) { return 2.0f / (1.0f + __expf(-2.0f * v)) - 1.0f; }

__device__ __forceinline__ void stxg_(float* p, float v) { *p = v; }
__device__ __forceinline__ void stxg_(__hip_bfloat16* p, float v) { *p = __float2bfloat16(v); }

// ---------------- Phase 1: xg GEMM, 128x128x16 tiles, 8x8 micro-tile ----------------
// Stores TRANSPOSED: xgT[m*4000 + e*4 + g]  (n = g*1000 + e)
template <typename XG>
__global__ __launch_bounds__(256) void xg_gemm2(
    const float* __restrict__ x,    // (T, 620)
    const float* __restrict__ Wih,  // (4000, 620)
    const float* __restrict__ bih,
    const float* __restrict__ bhh,
    XG* __restrict__ xg,            // (T, 4000) transposed-inner
    int T)
{
    constexpr int BM = 128, BN = 128, BK = 16, LDT = BM + 4;
    __shared__ float As[BK][LDT];
    __shared__ float Bs[BK][LDT];
    const int tid = threadIdx.x;
    const int tx = tid & 15, ty = tid >> 4;
    const int m0 = blockIdx.y * BM, n0 = blockIdx.x * BN;
    float acc[8][8] = {};

    for (int k0 = 0; k0 < IN_SZ; k0 += BK) {
        #pragma unroll
        for (int it = 0; it < 2; ++it) {
            const int r = (tid >> 2) + it * 64;
            const int c = (tid & 3) * 4;
            const int gk = k0 + c;
            {
                const int gm = m0 + r;
                float4 v = {0.f, 0.f, 0.f, 0.f};
                if (gm < T) {
                    if (gk + 3 < IN_SZ) {
                        v = *reinterpret_cast<const float4*>(x + (size_t)gm * IN_SZ + gk);
                    } else {
                        const float* row = x + (size_t)gm * IN_SZ;
                        v.x = (gk + 0 < IN_SZ) ? row[gk + 0] : 0.f;
                        v.y = (gk + 1 < IN_SZ) ? row[gk + 1] : 0.f;
                        v.z = (gk + 2 < IN_SZ) ? row[gk + 2] : 0.f;
                        v.w = (gk + 3 < IN_SZ) ? row[gk + 3] : 0.f;
                    }
                }
                As[c + 0][r] = v.x; As[c + 1][r] = v.y;
                As[c + 2][r] = v.z; As[c + 3][r] = v.w;
            }
            {
                const int gn = n0 + r;
                float4 v = {0.f, 0.f, 0.f, 0.f};
                if (gn < G4) {
                    if (gk + 3 < IN_SZ) {
                        v = *reinterpret_cast<const float4*>(Wih + (size_t)gn * IN_SZ + gk);
                    } else {
                        const float* row = Wih + (size_t)gn * IN_SZ;
                        v.x = (gk + 0 < IN_SZ) ? row[gk + 0] : 0.f;
                        v.y = (gk + 1 < IN_SZ) ? row[gk + 1] : 0.f;
                        v.z = (gk + 2 < IN_SZ) ? row[gk + 2] : 0.f;
                        v.w = (gk + 3 < IN_SZ) ? row[gk + 3] : 0.f;
                    }
                }
                Bs[c + 0][r] = v.x; Bs[c + 1][r] = v.y;
                Bs[c + 2][r] = v.z; Bs[c + 3][r] = v.w;
            }
        }
        __syncthreads();
        #pragma unroll
        for (int k = 0; k < BK; ++k) {
            float a[8], b[8];
            *reinterpret_cast<float4*>(&a[0]) = *reinterpret_cast<const float4*>(&As[k][ty * 8]);
            *reinterpret_cast<float4*>(&a[4]) = *reinterpret_cast<const float4*>(&As[k][ty * 8 + 4]);
            *reinterpret_cast<float4*>(&b[0]) = *reinterpret_cast<const float4*>(&Bs[k][tx * 8]);
            *reinterpret_cast<float4*>(&b[4]) = *reinterpret_cast<const float4*>(&Bs[k][tx * 8 + 4]);
            #pragma unroll
            for (int i = 0; i < 8; ++i)
                #pragma unroll
                for (int j = 0; j < 8; ++j)
                    acc[i][j] = fmaf(a[i], b[j], acc[i][j]);
        }
        __syncthreads();
    }

    float bias[8];
    #pragma unroll
    for (int j = 0; j < 8; ++j) {
        const int n = n0 + tx * 8 + j;
        bias[j] = (n < G4) ? (bih[n] + bhh[n]) : 0.f;
    }
    #pragma unroll
    for (int i = 0; i < 8; ++i) {
        const int m = m0 + ty * 8 + i;
        if (m >= T) continue;
        #pragma unroll
        for (int j = 0; j < 8; ++j) {
            const int n = n0 + tx * 8 + j;
            if (n < G4) {
                const int g = n / 1000, e = n - g * 1000;
                stxg_(&xg[(size_t)m * G4 + e * 4 + g], acc[i][j] + bias[j]);
            }
        }
    }
}

// ---------------- Phase 2: register-resident recurrent kernel ----------------
template <int MODE>
__device__ __forceinline__ float ldxg(const void* xg_v, size_t idx) {
    if (MODE == 0) return ((const float*)xg_v)[idx];
    return __bfloat162float(((const __hip_bfloat16*)xg_v)[idx]);
}

template <int MODE>
__global__ __launch_bounds__(256, 1) void lstm_fast(
    const void* __restrict__ xg_v,   // xgT (T,4000) [e*4+g]
    const float* __restrict__ Whh,   // (4000, 1000)
    float* __restrict__ out,         // (T, 1000)
    unsigned* hb_u,                  // 2 * 1024 u32 (double-buffered, stamped)
    int T)
{
    __shared__ __align__(16) unsigned hs[2][1024];
    __shared__ float gsum[4][4][2];  // [src wave][gate][elem parity]

    const int w = blockIdx.x, tid = threadIdx.x;
    const int wave = tid >> 6, lane = tid & 63;
    const int i16 = lane & 15, p = lane >> 4;       // p = gate for the dot
    const int we0 = w * 8 + wave * 2;               // this wave's 2 h-elements

    for (int i = tid; i < 2048; i += 256) ((unsigned*)hs)[i] = 0u;
    __syncthreads();

    // ---- weight preload into registers: rows (p*HID + we0), (.. + 1) ----
    const size_t rowA = (size_t)(p * HID + we0) * HID;
    const size_t rowB = rowA + HID;
    float4 wA[16], wB[16], hreg[16];
    #pragma unroll
    for (int m = 0; m < 15; ++m) {
        wA[m] = *reinterpret_cast<const float4*>(Whh + rowA + i16 * 4 + m * 64);
        wB[m] = *reinterpret_cast<const float4*>(Whh + rowB + i16 * 4 + m * 64);
    }
    if (i16 < 10) {
        wA[15] = *reinterpret_cast<const float4*>(Whh + rowA + 960 + i16 * 4);
        wB[15] = *reinterpret_cast<const float4*>(Whh + rowB + 960 + i16 * 4);
    } else {
        wA[15] = float4{0.f, 0.f, 0.f, 0.f};
        wB[15] = float4{0.f, 0.f, 0.f, 0.f};
    }

    // ---- wave-0 gate-lane mapping: lanes 0..31 ----
    const int gv_ = (lane >> 3) & 3;   // source wave v
    const int gp  = (lane >> 1) & 3;   // gate
    const int ge  = lane & 1;          // elem parity
    const int eg  = w * 8 + gv_ * 2 + ge;      // global h index for this lane
    const int xoff = (gv_ * 2 + ge) * 4 + gp;  // offset in WG's 32-dword xg slab
    const int shbase = (lane & ~7) | ge;       // owner-lane base for shfl combine
    float c_reg = 0.0f;                        // owner lanes (gp==0) of wave 0
    float xv = 0.0f;
    if (wave == 0 && lane < 32)
        xv = ldxg<MODE>(xg_v, (size_t)w * 32 + xoff);

    // ---- gather mapping (waves 1-3; 192 threads, dup-free tail) ----
    const int tid2 = tid - 64;                     // 0..191
    const int iA = tid2;
    const int iB = (tid2 < 58) ? (192 + tid2) : tid2;  // tail slots 192..249

    for (int t = 0;;) {
        const int rb = t & 1;

        // ---- h slice LDS -> regs ----
        #pragma unroll
        for (int m = 0; m < 15; ++m)
            hreg[m] = *reinterpret_cast<const float4*>(&hs[rb][i16 * 4 + m * 64]);
        hreg[15] = *reinterpret_cast<const float4*>(&hs[rb][960 + i16 * 4]);

        // ---- dot: 2 rows x 64 floats per lane ----
        float a0 = 0.f, a1 = 0.f, a2 = 0.f, a3 = 0.f;
        float b0 = 0.f, b1 = 0.f, b2 = 0.f, b3 = 0.f;
        #pragma unroll
        for (int m = 0; m < 16; ++m) {
            const float4 hv = hreg[m];
            const float sA = fmaf(wA[m].x, hv.x, fmaf(wA[m].y, hv.y,
                             fmaf(wA[m].z, hv.z, wA[m].w * hv.w)));
            const float sB = fmaf(wB[m].x, hv.x, fmaf(wB[m].y, hv.y,
                             fmaf(wB[m].z, hv.z, wB[m].w * hv.w)));
            if ((m & 3) == 0)      { a0 += sA; b0 += sB; }
            else if ((m & 3) == 1) { a1 += sA; b1 += sB; }
            else if ((m & 3) == 2) { a2 += sA; b2 += sB; }
            else                   { a3 += sA; b3 += sB; }
        }
        float rA = (a0 + a1) + (a2 + a3);
        float rB = (b0 + b1) + (b2 + b3);
        rA += __shfl_xor(rA, 1); rB += __shfl_xor(rB, 1);
        rA += __shfl_xor(rA, 2); rB += __shfl_xor(rB, 2);
        rA += __shfl_xor(rA, 4); rB += __shfl_xor(rB, 4);
        rA += __shfl_xor(rA, 8); rB += __shfl_xor(rB, 8);
        if (i16 == 0) { gsum[wave][p][0] = rA; gsum[wave][p][1] = rB; }
        __syncthreads();   // bar1: gsum complete, hs[rb] reads done

        // ---- wave 0: parallel gates, cell update, stamped publish ----
        if (wave == 0) {
            // issue next-step xg load first: independent of gates, lands
            // under the gate math (only in wave 0's vmcnt)
            float xv_next = 0.0f;
            if (lane < 32 && t + 1 < T)
                xv_next = ldxg<MODE>(xg_v, (size_t)(t + 1) * G4 + w * 32 + xoff);

            const float g = gsum[gv_][gp][ge] + xv;
            const float act = (gp == 2) ? tanh_fast(g) : sigm(g);
            const float iv = __shfl(act, shbase);
            const float fv = __shfl(act, shbase + 2);
            const float g2 = __shfl(act, shbase + 4);
            const float ov = __shfl(act, shbase + 6);
            if (lane < 32 && gp == 0) {    // owner lanes: v*8 + e
                c_reg = fv * c_reg + iv * g2;
                const float h = ov * tanh_fast(c_reg);
                const unsigned hb = (__float_as_uint(h) & ~3u) | (unsigned)((t + 1) & 3);
                // publish FIRST (sc0sc1 write-through to the coherence point)
                __hip_atomic_store(hb_u + rb * 1024 + eg, hb,
                                   __ATOMIC_RELAXED, __HIP_MEMORY_SCOPE_AGENT);
                out[(size_t)t * HID + eg] = h;
            }
            xv = xv_next;
        }

        if (++t >= T) break;

        // ---- waves 1-3: retry-gather stamped h with clean vmcnt ----
        if (wave > 0) {
            const unsigned want = (unsigned)t & 3u;        // stamp of h^{t-1}
            const uint4* srcb =
                reinterpret_cast<const uint4*>(hb_u + ((t - 1) & 1) * 1024);
            // align first probe past publish visibility (~192 cy): first
            // attempt then samples the LLC after the stores committed,
            // saving a full retry round-trip in the common case
            __builtin_amdgcn_s_sleep(3);
            uint4 vA, vB;
            for (;;) {
                asm volatile("global_load_dwordx4 %0, %2, off sc0 sc1\n\t"
                             "global_load_dwordx4 %1, %3, off sc0 sc1\n\t"
                             "s_waitcnt vmcnt(0)"
                             : "=&v"(vA), "=&v"(vB)
                             : "v"(srcb + iA), "v"(srcb + iB)
                             : "memory");
                const unsigned bad =
                    ((vA.x ^ want) | (vA.y ^ want) | (vA.z ^ want) | (vA.w ^ want) |
                     (vB.x ^ want) | (vB.y ^ want) | (vB.z ^ want) | (vB.w ^ want)) & 3u;
                if (bad == 0u) break;
            }
            uint4* dst = reinterpret_cast<uint4*>(&hs[t & 1][0]);
            dst[iA] = vA;
            if (tid2 < 58) dst[iB] = vB;   // tail slots, no duplicate writes
        }
        __syncthreads();   // bar2: hs[t&1] ready
    }
}

// ---------------- legacy fallback (tiny ws): fused x-projection ----------------
__global__ __launch_bounds__(256, 1) void lstm_seq_legacy(
    const float* __restrict__ x,
    const float* __restrict__ Wih,
    const float* __restrict__ Whh,
    const float* __restrict__ bih,
    const float* __restrict__ bhh,
    float* __restrict__ out,
    float* hbuf, unsigned* flags, int T)
{
    __shared__ __align__(16) float h_s[HID];
    __shared__ __align__(16) float x_s[IN_SZ + 4];
    __shared__ float pre[4][EP_LEG];

    const int w = blockIdx.x, tid = threadIdx.x;
    const int wave = tid >> 6, lane = tid & 63;
    const int i16 = lane & 15, p = lane >> 4;
    const int e0 = w * EP_LEG;

    for (int i = tid; i < HID; i += 256) h_s[i] = 0.0f;
    for (int i = tid; i < IN_SZ; i += 256) x_s[i] = x[i];
    __syncthreads();

    const float* wb_h = Whh + ((size_t)wave * HID + e0) * HID;
    const float* wb_x = Wih + ((size_t)wave * HID + e0) * IN_SZ;
    float c_reg = 0.0f;
    float bsum[4] = {0.f, 0.f, 0.f, 0.f};
    if (wave == 0 && lane < EP_LEG) {
        #pragma unroll
        for (int g = 0; g < 4; ++g) {
            int n = g * HID + e0 + lane;
            bsum[g] = bih[n] + bhh[n];
        }
    }

    for (int t = 0;;) {
        #pragma unroll
        for (int pass = 0; pass < EP_LEG / 4; ++pass) {
            const int e = pass * 4 + p;
            const float* wr = wb_h + (size_t)e * HID;
            float a0 = 0.f, a1 = 0.f, a2 = 0.f, a3 = 0.f;
            #pragma unroll
            for (int m = 0; m < 15; ++m) {
                const int kk = i16 * 4 + m * 64;
                const float4 wv = *reinterpret_cast<const float4*>(wr + kk);
                const float4 hv = *reinterpret_cast<const float4*>(&h_s[kk]);
                const float s = fmaf(wv.x, hv.x, fmaf(wv.y, hv.y, fmaf(wv.z, hv.z, wv.w * hv.w)));
                if ((m & 3) == 0) a0 += s; else if ((m & 3) == 1) a1 += s;
                else if ((m & 3) == 2) a2 += s; else a3 += s;
            }
            if (i16 < 10) {
                const int kk = i16 * 4 + 960;
                const float4 wv = *reinterpret_cast<const float4*>(wr + kk);
                const float4 hv = *reinterpret_cast<const float4*>(&h_s[kk]);
                a3 += fmaf(wv.x, hv.x, fmaf(wv.y, hv.y, fmaf(wv.z, hv.z, wv.w * hv.w)));
            }
            const float* wrx = wb_x + (size_t)e * IN_SZ;
            #pragma unroll
            for (int m = 0; m < 9; ++m) {
                const int kk = i16 * 4 + m * 64;
                const float4 wv = *reinterpret_cast<const float4*>(wrx + kk);
                const float4 hv = *reinterpret_cast<const float4*>(&x_s[kk]);
                const float s = fmaf(wv.x, hv.x, fmaf(wv.y, hv.y, fmaf(wv.z, hv.z, wv.w * hv.w)));
                if ((m & 3) == 0) a0 += s; else if ((m & 3) == 1) a1 += s;
                else if ((m & 3) == 2) a2 += s; else a3 += s;
            }
            if (i16 < 11) {
                const int kk = i16 * 4 + 576;
                const float4 wv = *reinterpret_cast<const float4*>(wrx + kk);
                const float4 hv = *reinterpret_cast<const float4*>(&x_s[kk]);
                a3 += fmaf(wv.x, hv.x, fmaf(wv.y, hv.y, fmaf(wv.z, hv.z, wv.w * hv.w)));
            }
            float acc = (a0 + a1) + (a2 + a3);
            acc += __shfl_xor(acc, 1);
            acc += __shfl_xor(acc, 2);
            acc += __shfl_xor(acc, 4);
            acc += __shfl_xor(acc, 8);
            if (i16 == 0) pre[wave][e] = acc;
        }
        __syncthreads();

        if (wave == 0 && lane < EP_LEG) {
            const float gi = pre[0][lane] + bsum[0];
            const float gf = pre[1][lane] + bsum[1];
            const float gg = pre[2][lane] + bsum[2];
            const float go = pre[3][lane] + bsum[3];
            const float iv = sigm(gi);
            const float fv = sigm(gf);
            const float gv = tanh_fast(gg);
            const float ov = sigm(go);
            c_reg = fv * c_reg + iv * gv;
            const float h = ov * tanh_fast(c_reg);
            out[(size_t)t * HID + e0 + lane] = h;
            __hip_atomic_store(&hbuf[(t & 1) * 1024 + e0 + lane], h,
                               __ATOMIC_RELAXED, __HIP_MEMORY_SCOPE_AGENT);
        }
        if (++t >= T) break;
        if (wave == 0 && lane == 0) {
            asm volatile("s_waitcnt vmcnt(0)" ::: "memory");
            __hip_atomic_store(&flags[w], (unsigned)t,
                               __ATOMIC_RELAXED, __HIP_MEMORY_SCOPE_AGENT);
        }
        if (wave > 0) {
            if (lane < NW_LEG) {
                while (__hip_atomic_load(&flags[lane], __ATOMIC_RELAXED,
                                         __HIP_MEMORY_SCOPE_AGENT) < (unsigned)t) {}
            }
            const int rb = tid - 64;
            for (int i = rb; i < HID; i += 192) {
                h_s[i] = __hip_atomic_load(&hbuf[((t - 1) & 1) * 1024 + i],
                                           __ATOMIC_RELAXED, __HIP_MEMORY_SCOPE_AGENT);
            }
            for (int i = rb; i < IN_SZ; i += 192) x_s[i] = x[(size_t)t * IN_SZ + i];
        }
        __syncthreads();
    }
}

// ---------------- launch ----------------
extern "C" void kernel_launch(void* const* d_in, const int* in_sizes, int n_in,
                              void* d_out, int out_size, void* d_ws, size_t ws_size,
                              hipStream_t stream)
{
    const float* x   = (const float*)d_in[0];
    const float* Wih = (const float*)d_in[1];
    const float* Whh = (const float*)d_in[2];
    const float* bih = (const float*)d_in[3];
    const float* bhh = (const float*)d_in[4];
    float* out = (float*)d_out;
    const int T = in_sizes[0] / IN_SZ;

    char* ws = (char*)d_ws;
    unsigned* hb_u  = (unsigned*)ws;           // 2*1024 u32 = 8 KB (stamped h)
    unsigned* flags = (unsigned*)(ws + 8192);  // legacy only
    const size_t CTRL = 16384;
    (void)hipMemsetAsync(d_ws, 0, CTRL, stream);  // zero stamps/flags every call

    const size_t need32 = CTRL + (size_t)T * G4 * sizeof(float);
    const size_t need16 = CTRL + (size_t)T * G4 * sizeof(__hip_bfloat16);

    dim3 g1((G4 + 127) / 128, (T + 127) / 128), b1(256);

    if (ws_size >= need32) {
        float* xgbuf = (float*)(ws + CTRL);
        xg_gemm2<float><<<g1, b1, 0, stream>>>(x, Wih, bih, bhh, xgbuf, T);
        lstm_fast<0><<<dim3(NWF), dim3(256), 0, stream>>>(xgbuf, Whh, out, hb_u, T);
    } else if (ws_size >= need16) {
        __hip_bfloat16* xgbuf = (__hip_bfloat16*)(ws + CTRL);
        xg_gemm2<__hip_bfloat16><<<g1, b1, 0, stream>>>(x, Wih, bih, bhh, xgbuf, T);
        lstm_fast<1><<<dim3(NWF), dim3(256), 0, stream>>>(xgbuf, Whh, out, hb_u, T);
    } else {
        lstm_seq_legacy<<<dim3(NW_LEG), dim3(256), 0, stream>>>(
            x, Wih, Whh, bih, bhh, out, (float*)hb_u, flags, T);
    }
}